// Round 9
// baseline (114.257 us; speedup 1.0000x reference)
//
#include <hip/hip_runtime.h>
#include <hip/hip_bf16.h>

typedef __attribute__((ext_vector_type(8))) __bf16 bf16x8;
typedef __attribute__((ext_vector_type(4))) float f32x4;

#define NROWS 16384
#define DIM   2048
#define NH1   512
#define NH2   32
#define MMEM  2048
#define BK    64
#define NT    (DIM / BK)   // 32 K-steps

// workspace byte offsets
#define W1O ((size_t)0)            // W1 bf16:  512*2048*2   = 2097152
#define W2O ((size_t)2097152)      // W2 bf16:  32*512*2     = 32768
#define AMO ((size_t)2129920)      // a_mem:    2048*32*2    = 131072
#define NMO ((size_t)2260992)      // n_mem:    2048*32*2    = 131072
#define HO  ((size_t)2392064)      // h bf16:   16384*512*2  = 16777216

__device__ __forceinline__ f32x4 mfma16(bf16x8 a, bf16x8 b, f32x4 c) {
    return __builtin_amdgcn_mfma_f32_16x16x32_bf16(a, b, c, 0, 0, 0);
}

__device__ __forceinline__ void gload_lds16(const void* g, void* l) {
    __builtin_amdgcn_global_load_lds(
        (const __attribute__((address_space(1))) void*)g,
        (__attribute__((address_space(3))) void*)l, 16, 0, 0);
}

__device__ __forceinline__ bf16x8 cvt8(f32x4 a, f32x4 b) {
    bf16x8 o;
    o[0] = (__bf16)a[0]; o[1] = (__bf16)a[1]; o[2] = (__bf16)a[2]; o[3] = (__bf16)a[3];
    o[4] = (__bf16)b[0]; o[5] = (__bf16)b[1]; o[6] = (__bf16)b[2]; o[7] = (__bf16)b[3];
    return o;
}

// ---------------- merged f32 -> bf16 conversion for W1, W2, am, nm ----------------
struct bf4 { __bf16 a, b, c, d; };

__global__ void cvt_all_kernel(const float* __restrict__ w1f, __bf16* __restrict__ w1b,
                               const float* __restrict__ w2f, __bf16* __restrict__ w2b,
                               const float* __restrict__ amf, __bf16* __restrict__ amb,
                               const float* __restrict__ nmf, __bf16* __restrict__ nmb) {
    const int g = blockIdx.x * blockDim.x + threadIdx.x;
    const int T = gridDim.x * blockDim.x;
    for (int i = g; i < (NH1 * DIM) / 4; i += T) {
        const float4 v = *reinterpret_cast<const float4*>(w1f + i * 4);
        *reinterpret_cast<bf4*>(w1b + i * 4) = { (__bf16)v.x, (__bf16)v.y, (__bf16)v.z, (__bf16)v.w };
    }
    for (int i = g; i < (NH2 * NH1) / 4; i += T) {
        const float4 v = *reinterpret_cast<const float4*>(w2f + i * 4);
        *reinterpret_cast<bf4*>(w2b + i * 4) = { (__bf16)v.x, (__bf16)v.y, (__bf16)v.z, (__bf16)v.w };
    }
    for (int i = g; i < (MMEM * NH2) / 4; i += T) {
        const float4 v = *reinterpret_cast<const float4*>(amf + i * 4);
        *reinterpret_cast<bf4*>(amb + i * 4) = { (__bf16)v.x, (__bf16)v.y, (__bf16)v.z, (__bf16)v.w };
    }
    for (int i = g; i < (MMEM * NH2) / 4; i += T) {
        const float4 v = *reinterpret_cast<const float4*>(nmf + i * 4);
        *reinterpret_cast<bf4*>(nmb + i * 4) = { (__bf16)v.x, (__bf16)v.y, (__bf16)v.z, (__bf16)v.w };
    }
}

// ---------------- GEMM1: h = relu(x @ W1^T + b1) ----------------
// 128x128 tile, BK=64, 4 waves (2x2, wave-tile 64x64) -> 32 MFMA/wave/step.
// Both LDS tiles bf16, 128-BYTE rows, slot ^= (row&7) (measured 0-conflict, R8).
// A: f32 reg-stage 1-deep -> cvt -> swizzled ds_write_b128.
// B: global_load_lds, pre-swizzled source, linear LDS dest.
// Counted-vmcnt barrier: B gloads issued first each iter, pa (A f32, 8 loads)
// issued last and left in flight across the barrier (vmcnt(8), never 0).
__global__ __launch_bounds__(256, 2) void gemm1_kernel(
    const float*  __restrict__ Xf,  // [NROWS][DIM] f32
    const __bf16* __restrict__ W1,  // [NH1][DIM] bf16
    const float*  __restrict__ b1,  // [NH1]
    __bf16* __restrict__ Hout)      // [NROWS][NH1]
{
    __shared__ __bf16 Ab[2][128 * BK];   // 16KB each
    __shared__ __bf16 Bb[2][128 * BK];   // 16KB each  (total 64KB -> 2 blocks/CU)
    const int tid  = threadIdx.x;
    const int lane = tid & 63;
    const int wave = tid >> 6;
    // XCD swizzle: nwg=512 = 8*64 (bijective).
    const int b = blockIdx.x;
    const int orig = (b & 7) * 64 + (b >> 3);
    const int bn = orig & 3;    // 4 col tiles of 128
    const int bm = orig >> 2;   // 128 row tiles of 128
    const size_t brow = (size_t)bm * 128;
    const int bcol = bn * 128;
    const int wr = wave >> 1, wc = wave & 1;

    f32x4 acc[4][4];
#pragma unroll
    for (int m = 0; m < 4; ++m)
#pragma unroll
        for (int n = 0; n < 4; ++n) acc[m][n] = (f32x4){0.f, 0.f, 0.f, 0.f};

    // ---- A staging (reg 1-deep): thread t covers row t>>1, k-half t&1 (32 f32).
    // Write 4 b128 at slots (half*4+j) ^ (row&7).
    const int aRow  = tid >> 1;
    const int aHalf = tid & 1;
    const float* aSrc = Xf + (brow + aRow) * (size_t)DIM + aHalf * 32;
    int aW[4];
#pragma unroll
    for (int j = 0; j < 4; ++j)
        aW[j] = aRow * 128 + (((aHalf * 4 + j) ^ (aRow & 7)) << 4);

    // ---- B staging (gload_lds): q in 0..3; row = q*32 + (tid>>3); stored slot
    // = tid&7; source chunk = (tid&7) ^ (row&7); LDS dst linear q*4096 + tid*16.
    const int bRowT  = tid >> 3;                      // 0..31
    const int bChunk = (tid & 7) ^ (bRowT & 7);
    const __bf16* bSrcBase = W1 + (size_t)(bcol + bRowT) * DIM + bChunk * 8;

#define STAGE_B(T, BI)                                                        \
    {                                                                         \
        const int k0_ = (T) * BK;                                             \
        _Pragma("unroll")                                                     \
        for (int q = 0; q < 4; ++q)                                           \
            gload_lds16(bSrcBase + (size_t)q * 32 * DIM + k0_,                \
                        (char*)Bb[BI] + q * 4096 + tid * 16);                 \
    }

#define WRITE_A(BI)                                                           \
    {                                                                         \
        _Pragma("unroll")                                                     \
        for (int j = 0; j < 4; ++j)                                           \
            *(bf16x8*)((char*)Ab[BI] + aW[j]) = cvt8(pa[2 * j], pa[2 * j + 1]); \
    }

#define LOAD_PA(T)                                                            \
    {                                                                         \
        const float* qs_ = aSrc + (size_t)(T) * BK;                           \
        _Pragma("unroll")                                                     \
        for (int i = 0; i < 8; ++i) pa[i] = *(const f32x4*)(qs_ + i * 4);     \
    }

    // ---- fragment read geometry: row&7 == lane&7 for all frags.
    const int l15 = lane & 15;
    const int kc  = lane >> 4;
    const int l7  = lane & 7;
    const int rABase = wr * 64 + l15;
    const int rBBase = wc * 64 + l15;

#define COMPUTE(BI)                                                           \
    {                                                                         \
        const char* Ac = (const char*)Ab[BI];                                 \
        const char* Bc = (const char*)Bb[BI];                                 \
        _Pragma("unroll")                                                     \
        for (int kk = 0; kk < 2; ++kk) {                                      \
            const int slot = ((kk * 4 + kc) ^ l7) << 4;                       \
            bf16x8 av[4], bv[4];                                              \
            _Pragma("unroll")                                                 \
            for (int m = 0; m < 4; ++m)                                       \
                av[m] = *(const bf16x8*)(Ac + (rABase + m * 16) * 128 + slot);\
            _Pragma("unroll")                                                 \
            for (int n = 0; n < 4; ++n)                                       \
                bv[n] = *(const bf16x8*)(Bc + (rBBase + n * 16) * 128 + slot);\
            _Pragma("unroll")                                                 \
            for (int m = 0; m < 4; ++m)                                       \
                _Pragma("unroll")                                             \
                for (int n = 0; n < 4; ++n)                                   \
                    acc[m][n] = mfma16(av[m], bv[n], acc[m][n]);              \
        }                                                                     \
    }

    f32x4 pa[8];

    // ===== prologue: B(0) gloads; A(0) via regs; pa = A(1) =====
    STAGE_B(0, 0);
    __builtin_amdgcn_sched_barrier(0);
    LOAD_PA(0);
    WRITE_A(0);          // auto-waits the A(0) loads only (newer than B gloads? no:
                         // B issued first -> oldest; wait for A(0) drains B too. Prologue only.
    LOAD_PA(1);
    __builtin_amdgcn_sched_barrier(0);
    asm volatile("s_waitcnt vmcnt(8) lgkmcnt(0)" ::: "memory");
    __builtin_amdgcn_s_barrier();
    __builtin_amdgcn_sched_barrier(0);

    // ===== main loop =====
    // iter t: [B(t+1) gloads first] [A(t+1) cvt-write: auto vmcnt waits only the
    // OLDER pa] [pa <- A(t+2), newest] COMPUTE(t) [vmcnt(8): drains the 4 B
    // gloads, leaves 8 pa in flight] barrier.
    for (int t = 0; t < NT; ++t) {
        if (t + 1 < NT) {
            const int nb = (t + 1) & 1;
            STAGE_B(t + 1, nb);
            __builtin_amdgcn_sched_barrier(0);
            WRITE_A(nb);
            const int tq = (t + 2 < NT) ? (t + 2) : (NT - 1);
            LOAD_PA(tq);
            __builtin_amdgcn_sched_barrier(0);
        }
        COMPUTE(t & 1);
        asm volatile("s_waitcnt vmcnt(8) lgkmcnt(0)" ::: "memory");
        __builtin_amdgcn_s_barrier();
        __builtin_amdgcn_sched_barrier(0);
    }
#undef STAGE_B
#undef WRITE_A
#undef LOAD_PA
#undef COMPUTE

    // epilogue: bias + relu + bf16 store. D layout: col=lane&15, row=(lane>>4)*4+reg
#pragma unroll
    for (int n = 0; n < 4; ++n) {
        const int gcol = bcol + wc * 64 + n * 16 + l15;
        const float bias = b1[gcol];
#pragma unroll
        for (int m = 0; m < 4; ++m) {
            const size_t grow0 = brow + wr * 64 + m * 16 + kc * 4;
#pragma unroll
            for (int r = 0; r < 4; ++r) {
                float v = acc[m][n][r] + bias;
                v = v > 0.f ? v : 0.f;
                Hout[(grow0 + r) * NH1 + gcol] = (__bf16)v;
            }
        }
    }
}

// ---------------- Tail: feat = h@W2^T + b2; scores; sigmoid ----------------
__global__ __launch_bounds__(512) void tail_kernel(
    const __bf16* __restrict__ Hin,  // [NROWS][NH1]
    const __bf16* __restrict__ W2b,  // [NH2][NH1]
    const float*  __restrict__ b2,   // [NH2]
    const __bf16* __restrict__ Am,   // [MMEM][NH2]
    const __bf16* __restrict__ Nm,   // [MMEM][NH2]
    float* __restrict__ out)         // [NROWS]
{
    __shared__ __bf16 featLds[64 * 32];
    __shared__ float aMaxLds[2][64];
    __shared__ float nMaxLds[2][64];
    const int tid  = threadIdx.x;
    const int lane = tid & 63;
    const int wave = tid >> 6;          // 0..7
    const int rowBase = blockIdx.x * 64;
    const int l15 = lane & 15;
    const int kc  = lane >> 4;
    const int rgrp  = (wave & 3) * 16;
    const int jHalf = wave >> 2;

    if (wave < 4) {
        f32x4 acc0 = {0.f,0.f,0.f,0.f}, acc1 = {0.f,0.f,0.f,0.f};
        const size_t hrow = (size_t)(rowBase + rgrp + l15) * NH1;
#pragma unroll
        for (int kk = 0; kk < 16; ++kk) {
            bf16x8 a  = *(const bf16x8*)(Hin + hrow + kk * 32 + kc * 8);
            bf16x8 w0 = *(const bf16x8*)(W2b + (size_t)l15 * NH1 + kk * 32 + kc * 8);
            bf16x8 w1 = *(const bf16x8*)(W2b + (size_t)(16 + l15) * NH1 + kk * 32 + kc * 8);
            acc0 = mfma16(a, w0, acc0);
            acc1 = mfma16(a, w1, acc1);
        }
        const float bias0 = b2[l15], bias1 = b2[16 + l15];
#pragma unroll
        for (int r = 0; r < 4; ++r) {
            const int lr = rgrp + kc * 4 + r;
            featLds[lr * 32 + l15]      = (__bf16)(acc0[r] + bias0);
            featLds[lr * 32 + 16 + l15] = (__bf16)(acc1[r] + bias1);
        }
    }
    __syncthreads();

    const bf16x8 af = *(const bf16x8*)&featLds[(rgrp + l15) * 32 + kc * 8];

    float rmaxA[4], rmaxN[4];
#pragma unroll
    for (int r = 0; r < 4; ++r) { rmaxA[r] = -1e30f; rmaxN[r] = -1e30f; }
    const f32x4 zero = {0.f,0.f,0.f,0.f};
    const int jBase = jHalf * (MMEM / 2);
#pragma unroll 2
    for (int jt = 0; jt < (MMEM / 2) / 16; jt += 4) {
        bf16x8 ba[4], bb[4];
#pragma unroll
        for (int u = 0; u < 4; ++u) {
            const size_t off = (size_t)(jBase + (jt + u) * 16 + l15) * NH2 + kc * 8;
            ba[u] = *(const bf16x8*)(Am + off);
            bb[u] = *(const bf16x8*)(Nm + off);
        }
#pragma unroll
        for (int u = 0; u < 4; ++u) {
            f32x4 sa = mfma16(af, ba[u], zero);
            f32x4 sn = mfma16(af, bb[u], zero);
#pragma unroll
            for (int r = 0; r < 4; ++r) {
                rmaxA[r] = fmaxf(rmaxA[r], sa[r]);
                rmaxN[r] = fmaxf(rmaxN[r], sn[r]);
            }
        }
    }
#pragma unroll
    for (int off = 1; off < 16; off <<= 1) {
#pragma unroll
        for (int r = 0; r < 4; ++r) {
            rmaxA[r] = fmaxf(rmaxA[r], __shfl_xor(rmaxA[r], off, 64));
            rmaxN[r] = fmaxf(rmaxN[r], __shfl_xor(rmaxN[r], off, 64));
        }
    }
    if (l15 == 0) {
#pragma unroll
        for (int r = 0; r < 4; ++r) {
            const int row = rgrp + kc * 4 + r;
            aMaxLds[jHalf][row] = rmaxA[r];
            nMaxLds[jHalf][row] = rmaxN[r];
        }
    }
    __syncthreads();
    if (tid < 64) {
        const float ma = fmaxf(aMaxLds[0][tid], aMaxLds[1][tid]);
        const float mn = fmaxf(nMaxLds[0][tid], nMaxLds[1][tid]);
        const float d = (ma - mn) * (1.0f / 32.0f);
        out[rowBase + tid] = 1.0f / (1.0f + __expf(-d));
    }
}

extern "C" void kernel_launch(void* const* d_in, const int* in_sizes, int n_in,
                              void* d_out, int out_size, void* d_ws, size_t ws_size,
                              hipStream_t stream) {
    (void)in_sizes; (void)n_in; (void)out_size; (void)ws_size;
    const float* x  = (const float*)d_in[0];
    const float* W1 = (const float*)d_in[1];
    const float* b1 = (const float*)d_in[2];
    const float* W2 = (const float*)d_in[3];
    const float* b2 = (const float*)d_in[4];
    const float* am = (const float*)d_in[5];
    const float* nm = (const float*)d_in[6];
    float* out = (float*)d_out;
    char* ws = (char*)d_ws;
    __bf16* w1b = (__bf16*)(ws + W1O);
    __bf16* w2b = (__bf16*)(ws + W2O);
    __bf16* amb = (__bf16*)(ws + AMO);
    __bf16* nmb = (__bf16*)(ws + NMO);
    __bf16* hb  = (__bf16*)(ws + HO);

    cvt_all_kernel<<<dim3(512), dim3(256), 0, stream>>>(W1, w1b, W2, w2b, am, amb, nm, nmb);
    gemm1_kernel<<<dim3((NROWS / 128) * (NH1 / 128)), dim3(256), 0, stream>>>(x, w1b, b1, hb);
    tail_kernel<<<dim3(NROWS / 64), dim3(512), 0, stream>>>(hb, w2b, b2, amb, nmb, out);
}

// Round 10
// 114.109 us; speedup vs baseline: 1.0013x; 1.0013x over previous
//
#include <hip/hip_runtime.h>
#include <hip/hip_bf16.h>

typedef __attribute__((ext_vector_type(8))) __bf16 bf16x8;
typedef __attribute__((ext_vector_type(4))) float f32x4;

#define NROWS 16384
#define DIM   2048
#define NH1   512
#define NH2   32
#define MMEM  2048
#define BK    64
#define NT    (DIM / BK)   // 32 K-steps

// workspace byte offsets
#define W1O ((size_t)0)            // W1 bf16:  512*2048*2   = 2097152
#define W2O ((size_t)2097152)      // W2 bf16:  32*512*2     = 32768
#define AMO ((size_t)2129920)      // a_mem:    2048*32*2    = 131072
#define NMO ((size_t)2260992)      // n_mem:    2048*32*2    = 131072
#define HO  ((size_t)2392064)      // h bf16:   16384*512*2  = 16777216

__device__ __forceinline__ f32x4 mfma16(bf16x8 a, bf16x8 b, f32x4 c) {
    return __builtin_amdgcn_mfma_f32_16x16x32_bf16(a, b, c, 0, 0, 0);
}

__device__ __forceinline__ void gload_lds16(const void* g, void* l) {
    __builtin_amdgcn_global_load_lds(
        (const __attribute__((address_space(1))) void*)g,
        (__attribute__((address_space(3))) void*)l, 16, 0, 0);
}

__device__ __forceinline__ bf16x8 cvt8(f32x4 a, f32x4 b) {
    bf16x8 o;
    o[0] = (__bf16)a[0]; o[1] = (__bf16)a[1]; o[2] = (__bf16)a[2]; o[3] = (__bf16)a[3];
    o[4] = (__bf16)b[0]; o[5] = (__bf16)b[1]; o[6] = (__bf16)b[2]; o[7] = (__bf16)b[3];
    return o;
}

// ---------------- merged f32 -> bf16 conversion for W1, W2, am, nm ----------------
struct bf4 { __bf16 a, b, c, d; };

__global__ void cvt_all_kernel(const float* __restrict__ w1f, __bf16* __restrict__ w1b,
                               const float* __restrict__ w2f, __bf16* __restrict__ w2b,
                               const float* __restrict__ amf, __bf16* __restrict__ amb,
                               const float* __restrict__ nmf, __bf16* __restrict__ nmb) {
    const int g = blockIdx.x * blockDim.x + threadIdx.x;
    const int T = gridDim.x * blockDim.x;
    for (int i = g; i < (NH1 * DIM) / 4; i += T) {
        const float4 v = *reinterpret_cast<const float4*>(w1f + i * 4);
        *reinterpret_cast<bf4*>(w1b + i * 4) = { (__bf16)v.x, (__bf16)v.y, (__bf16)v.z, (__bf16)v.w };
    }
    for (int i = g; i < (NH2 * NH1) / 4; i += T) {
        const float4 v = *reinterpret_cast<const float4*>(w2f + i * 4);
        *reinterpret_cast<bf4*>(w2b + i * 4) = { (__bf16)v.x, (__bf16)v.y, (__bf16)v.z, (__bf16)v.w };
    }
    for (int i = g; i < (MMEM * NH2) / 4; i += T) {
        const float4 v = *reinterpret_cast<const float4*>(amf + i * 4);
        *reinterpret_cast<bf4*>(amb + i * 4) = { (__bf16)v.x, (__bf16)v.y, (__bf16)v.z, (__bf16)v.w };
    }
    for (int i = g; i < (MMEM * NH2) / 4; i += T) {
        const float4 v = *reinterpret_cast<const float4*>(nmf + i * 4);
        *reinterpret_cast<bf4*>(nmb + i * 4) = { (__bf16)v.x, (__bf16)v.y, (__bf16)v.z, (__bf16)v.w };
    }
}

// ---------------- GEMM1: h = relu(x @ W1^T + b1) ----------------
// 128x128 tile, BK=64, 4 waves (2x2, wave-tile 64x64) -> 32 MFMA/wave/step.
// A (x, f32): LDS via global_load_lds, double-buffered 2x32KB, 256B rows,
//   16-slot XOR swizzle slot^=(row&15) (read: 16 lanes -> 16 distinct slots).
//   cvt f32->bf16 at fragment read.
// B (W1, bf16, 2MB = L2-resident): NO LDS. Per-lane direct global dwordx4
//   fragments, double-buffered in regs (8+8), prefetched 1 K-step ahead.
// One s_barrier + vmcnt(8)/lgkmcnt(0) per step (B prefetch stays in flight).
__global__ __launch_bounds__(256, 2) void gemm1_kernel(
    const float*  __restrict__ Xf,  // [NROWS][DIM] f32
    const __bf16* __restrict__ W1,  // [NH1][DIM] bf16
    const float*  __restrict__ b1,  // [NH1]
    __bf16* __restrict__ Hout)      // [NROWS][NH1]
{
    __shared__ float Ab[2][128 * BK];   // 32KB each, 64KB total -> 2 blocks/CU
    const int tid  = threadIdx.x;
    const int lane = tid & 63;
    const int wave = tid >> 6;
    // XCD swizzle: nwg=512 = 8*64 (bijective).
    const int b = blockIdx.x;
    const int orig = (b & 7) * 64 + (b >> 3);
    const int bn = orig & 3;    // 4 col tiles of 128
    const int bm = orig >> 2;   // 128 row tiles of 128
    const size_t brow = (size_t)bm * 128;
    const int bcol = bn * 128;
    const int wr = wave >> 1, wc = wave & 1;

    f32x4 acc[4][4];
#pragma unroll
    for (int m = 0; m < 4; ++m)
#pragma unroll
        for (int n = 0; n < 4; ++n) acc[m][n] = (f32x4){0.f, 0.f, 0.f, 0.f};

    // ---- A staging: 8 gloads/thread. LDS linear: q*4096 + tid*16 ->
    // row = q*16 + (tid>>4), stored 16B-slot = tid&15 (256B rows, 16 slots).
    // stored slot s holds logical slot s ^ (row&15): source chunk =
    // (tid&15) ^ ((tid>>4)&15).
    const int aRowT = tid >> 4;                 // 0..15
    const int cA    = (tid & 15) ^ aRowT;       // source 16B-chunk in 256B row
    const float* aSrcBase = Xf + (brow + aRowT) * (size_t)DIM + cA * 4;

#define STAGE_A(T, BI)                                                        \
    {                                                                         \
        _Pragma("unroll")                                                     \
        for (int q = 0; q < 8; ++q)                                           \
            gload_lds16(aSrcBase + (size_t)q * 16 * DIM + (T) * BK,           \
                        (char*)Ab[BI] + q * 4096 + tid * 16);                 \
    }

    // ---- B direct-from-global fragments (no LDS)
    const int l15 = lane & 15;
    const int kc  = lane >> 4;
    const __bf16* bBase = W1 + (size_t)(bcol + wc * 64 + l15) * DIM + kc * 8;

#define LOAD_BV(T, DST)                                                       \
    {                                                                         \
        _Pragma("unroll")                                                     \
        for (int n = 0; n < 4; ++n) {                                         \
            DST[n * 2]     = *(const bf16x8*)(bBase + (size_t)(n * 16) * DIM + (T) * BK);      \
            DST[n * 2 + 1] = *(const bf16x8*)(bBase + (size_t)(n * 16) * DIM + (T) * BK + 32); \
        }                                                                     \
    }

    // ---- A fragment read: row = rABase + m*16 (row&15 == l15);
    // logical slot = kk*8 + kc*2 + j  ->  stored = logical ^ l15.
    const int rABase = wr * 64 + l15;

#define COMPUTE(BI, BV)                                                       \
    {                                                                         \
        const char* Ac = (const char*)Ab[BI];                                 \
        _Pragma("unroll")                                                     \
        for (int kk = 0; kk < 2; ++kk) {                                      \
            bf16x8 av[4];                                                     \
            _Pragma("unroll")                                                 \
            for (int m = 0; m < 4; ++m) {                                     \
                const char* rp = Ac + (rABase + m * 16) * 256;                \
                f32x4 lo = *(const f32x4*)(rp + (((kk * 8 + kc * 2)     ^ l15) << 4)); \
                f32x4 hi = *(const f32x4*)(rp + (((kk * 8 + kc * 2 + 1) ^ l15) << 4)); \
                av[m] = cvt8(lo, hi);                                         \
            }                                                                 \
            _Pragma("unroll")                                                 \
            for (int m = 0; m < 4; ++m)                                       \
                _Pragma("unroll")                                             \
                for (int n = 0; n < 4; ++n)                                   \
                    acc[m][n] = mfma16(av[m], BV[n * 2 + kk], acc[m][n]);     \
        }                                                                     \
    }

    bf16x8 bva[8], bvb[8];

    // ===== prologue: A(0) staged, bva = B(0); drain-all once =====
    STAGE_A(0, 0);
    LOAD_BV(0, bva);
    __builtin_amdgcn_sched_barrier(0);
    asm volatile("s_waitcnt vmcnt(0)" ::: "memory");
    __builtin_amdgcn_s_barrier();

    // ===== main loop (2x unrolled for static bva/bvb) =====
    // half-iter t: STAGE_A(t+1) + LOAD_BV(t+1, other) | COMPUTE(t, cur) |
    // vmcnt(8) [drains A(t+1), leaves the 8 B loads in flight] lgkmcnt(0) barrier.
#pragma unroll 1
    for (int t = 0; t < NT; t += 2) {
        // even half: compute t (buf 0, bva); stage t+1 (buf 1), load bvb
        STAGE_A(t + 1, 1);
        LOAD_BV(t + 1, bvb);
        __builtin_amdgcn_sched_barrier(0);
        COMPUTE(0, bva);
        asm volatile("s_waitcnt vmcnt(8) lgkmcnt(0)" ::: "memory");
        __builtin_amdgcn_s_barrier();
        // odd half: compute t+1 (buf 1, bvb); stage t+2 (buf 0), load bva
        if (t + 2 < NT) {
            STAGE_A(t + 2, 0);
            LOAD_BV(t + 2, bva);
        }
        __builtin_amdgcn_sched_barrier(0);
        COMPUTE(1, bvb);
        asm volatile("s_waitcnt vmcnt(8) lgkmcnt(0)" ::: "memory");
        __builtin_amdgcn_s_barrier();
    }
#undef STAGE_A
#undef LOAD_BV
#undef COMPUTE

    // epilogue: bias + relu + bf16 store. D layout: col=lane&15, row=(lane>>4)*4+reg
#pragma unroll
    for (int n = 0; n < 4; ++n) {
        const int gcol = bcol + wc * 64 + n * 16 + l15;
        const float bias = b1[gcol];
#pragma unroll
        for (int m = 0; m < 4; ++m) {
            const size_t grow0 = brow + wr * 64 + m * 16 + kc * 4;
#pragma unroll
            for (int r = 0; r < 4; ++r) {
                float v = acc[m][n][r] + bias;
                v = v > 0.f ? v : 0.f;
                Hout[(grow0 + r) * NH1 + gcol] = (__bf16)v;
            }
        }
    }
}

// ---------------- Tail: feat = h@W2^T + b2; scores; sigmoid ----------------
__global__ __launch_bounds__(512) void tail_kernel(
    const __bf16* __restrict__ Hin,  // [NROWS][NH1]
    const __bf16* __restrict__ W2b,  // [NH2][NH1]
    const float*  __restrict__ b2,   // [NH2]
    const __bf16* __restrict__ Am,   // [MMEM][NH2]
    const __bf16* __restrict__ Nm,   // [MMEM][NH2]
    float* __restrict__ out)         // [NROWS]
{
    __shared__ __bf16 featLds[64 * 32];
    __shared__ float aMaxLds[2][64];
    __shared__ float nMaxLds[2][64];
    const int tid  = threadIdx.x;
    const int lane = tid & 63;
    const int wave = tid >> 6;          // 0..7
    const int rowBase = blockIdx.x * 64;
    const int l15 = lane & 15;
    const int kc  = lane >> 4;
    const int rgrp  = (wave & 3) * 16;
    const int jHalf = wave >> 2;

    if (wave < 4) {
        f32x4 acc0 = {0.f,0.f,0.f,0.f}, acc1 = {0.f,0.f,0.f,0.f};
        const size_t hrow = (size_t)(rowBase + rgrp + l15) * NH1;
#pragma unroll
        for (int kk = 0; kk < 16; ++kk) {
            bf16x8 a  = *(const bf16x8*)(Hin + hrow + kk * 32 + kc * 8);
            bf16x8 w0 = *(const bf16x8*)(W2b + (size_t)l15 * NH1 + kk * 32 + kc * 8);
            bf16x8 w1 = *(const bf16x8*)(W2b + (size_t)(16 + l15) * NH1 + kk * 32 + kc * 8);
            acc0 = mfma16(a, w0, acc0);
            acc1 = mfma16(a, w1, acc1);
        }
        const float bias0 = b2[l15], bias1 = b2[16 + l15];
#pragma unroll
        for (int r = 0; r < 4; ++r) {
            const int lr = rgrp + kc * 4 + r;
            featLds[lr * 32 + l15]      = (__bf16)(acc0[r] + bias0);
            featLds[lr * 32 + 16 + l15] = (__bf16)(acc1[r] + bias1);
        }
    }
    __syncthreads();

    const bf16x8 af = *(const bf16x8*)&featLds[(rgrp + l15) * 32 + kc * 8];

    float rmaxA[4], rmaxN[4];
#pragma unroll
    for (int r = 0; r < 4; ++r) { rmaxA[r] = -1e30f; rmaxN[r] = -1e30f; }
    const f32x4 zero = {0.f,0.f,0.f,0.f};
    const int jBase = jHalf * (MMEM / 2);
#pragma unroll 2
    for (int jt = 0; jt < (MMEM / 2) / 16; jt += 4) {
        bf16x8 ba[4], bb[4];
#pragma unroll
        for (int u = 0; u < 4; ++u) {
            const size_t off = (size_t)(jBase + (jt + u) * 16 + l15) * NH2 + kc * 8;
            ba[u] = *(const bf16x8*)(Am + off);
            bb[u] = *(const bf16x8*)(Nm + off);
        }
#pragma unroll
        for (int u = 0; u < 4; ++u) {
            f32x4 sa = mfma16(af, ba[u], zero);
            f32x4 sn = mfma16(af, bb[u], zero);
#pragma unroll
            for (int r = 0; r < 4; ++r) {
                rmaxA[r] = fmaxf(rmaxA[r], sa[r]);
                rmaxN[r] = fmaxf(rmaxN[r], sn[r]);
            }
        }
    }
#pragma unroll
    for (int off = 1; off < 16; off <<= 1) {
#pragma unroll
        for (int r = 0; r < 4; ++r) {
            rmaxA[r] = fmaxf(rmaxA[r], __shfl_xor(rmaxA[r], off, 64));
            rmaxN[r] = fmaxf(rmaxN[r], __shfl_xor(rmaxN[r], off, 64));
        }
    }
    if (l15 == 0) {
#pragma unroll
        for (int r = 0; r < 4; ++r) {
            const int row = rgrp + kc * 4 + r;
            aMaxLds[jHalf][row] = rmaxA[r];
            nMaxLds[jHalf][row] = rmaxN[r];
        }
    }
    __syncthreads();
    if (tid < 64) {
        const float ma = fmaxf(aMaxLds[0][tid], aMaxLds[1][tid]);
        const float mn = fmaxf(nMaxLds[0][tid], nMaxLds[1][tid]);
        const float d = (ma - mn) * (1.0f / 32.0f);
        out[rowBase + tid] = 1.0f / (1.0f + __expf(-d));
    }
}

extern "C" void kernel_launch(void* const* d_in, const int* in_sizes, int n_in,
                              void* d_out, int out_size, void* d_ws, size_t ws_size,
                              hipStream_t stream) {
    (void)in_sizes; (void)n_in; (void)out_size; (void)ws_size;
    const float* x  = (const float*)d_in[0];
    const float* W1 = (const float*)d_in[1];
    const float* b1 = (const float*)d_in[2];
    const float* W2 = (const float*)d_in[3];
    const float* b2 = (const float*)d_in[4];
    const float* am = (const float*)d_in[5];
    const float* nm = (const float*)d_in[6];
    float* out = (float*)d_out;
    char* ws = (char*)d_ws;
    __bf16* w1b = (__bf16*)(ws + W1O);
    __bf16* w2b = (__bf16*)(ws + W2O);
    __bf16* amb = (__bf16*)(ws + AMO);
    __bf16* nmb = (__bf16*)(ws + NMO);
    __bf16* hb  = (__bf16*)(ws + HO);

    cvt_all_kernel<<<dim3(512), dim3(256), 0, stream>>>(W1, w1b, W2, w2b, am, amb, nm, nmb);
    gemm1_kernel<<<dim3((NROWS / 128) * (NH1 / 128)), dim3(256), 0, stream>>>(x, w1b, b1, hb);
    tail_kernel<<<dim3(NROWS / 64), dim3(512), 0, stream>>>(hb, w2b, b2, amb, nmb, out);
}

// Round 11
// 111.069 us; speedup vs baseline: 1.0287x; 1.0274x over previous
//
#include <hip/hip_runtime.h>
#include <hip/hip_bf16.h>

typedef __attribute__((ext_vector_type(8))) __bf16 bf16x8;
typedef __attribute__((ext_vector_type(4))) float f32x4;

#define NROWS 16384
#define DIM   2048
#define NH1   512
#define NH2   32
#define MMEM  2048
#define BK    32
#define NT    (DIM / BK)   // 64 K-steps

// workspace byte offsets
#define W1O ((size_t)0)            // W1 bf16:  512*2048*2   = 2097152
#define W2O ((size_t)2097152)      // W2 bf16:  32*512*2     = 32768
#define AMO ((size_t)2129920)      // a_mem:    2048*32*2    = 131072
#define NMO ((size_t)2260992)      // n_mem:    2048*32*2    = 131072
#define HO  ((size_t)2392064)      // h bf16:   16384*512*2  = 16777216

__device__ __forceinline__ f32x4 mfma16(bf16x8 a, bf16x8 b, f32x4 c) {
    return __builtin_amdgcn_mfma_f32_16x16x32_bf16(a, b, c, 0, 0, 0);
}

__device__ __forceinline__ void gload_lds16(const void* g, void* l) {
    __builtin_amdgcn_global_load_lds(
        (const __attribute__((address_space(1))) void*)g,
        (__attribute__((address_space(3))) void*)l, 16, 0, 0);
}

__device__ __forceinline__ bf16x8 cvt8(f32x4 a, f32x4 b) {
    bf16x8 o;
    o[0] = (__bf16)a[0]; o[1] = (__bf16)a[1]; o[2] = (__bf16)a[2]; o[3] = (__bf16)a[3];
    o[4] = (__bf16)b[0]; o[5] = (__bf16)b[1]; o[6] = (__bf16)b[2]; o[7] = (__bf16)b[3];
    return o;
}

// ---------------- merged f32 -> bf16 conversion for W1, W2, am, nm ----------------
struct bf4 { __bf16 a, b, c, d; };

__global__ void cvt_all_kernel(const float* __restrict__ w1f, __bf16* __restrict__ w1b,
                               const float* __restrict__ w2f, __bf16* __restrict__ w2b,
                               const float* __restrict__ amf, __bf16* __restrict__ amb,
                               const float* __restrict__ nmf, __bf16* __restrict__ nmb) {
    const int g = blockIdx.x * blockDim.x + threadIdx.x;
    const int T = gridDim.x * blockDim.x;
    for (int i = g; i < (NH1 * DIM) / 4; i += T) {
        const float4 v = *reinterpret_cast<const float4*>(w1f + i * 4);
        *reinterpret_cast<bf4*>(w1b + i * 4) = { (__bf16)v.x, (__bf16)v.y, (__bf16)v.z, (__bf16)v.w };
    }
    for (int i = g; i < (NH2 * NH1) / 4; i += T) {
        const float4 v = *reinterpret_cast<const float4*>(w2f + i * 4);
        *reinterpret_cast<bf4*>(w2b + i * 4) = { (__bf16)v.x, (__bf16)v.y, (__bf16)v.z, (__bf16)v.w };
    }
    for (int i = g; i < (MMEM * NH2) / 4; i += T) {
        const float4 v = *reinterpret_cast<const float4*>(amf + i * 4);
        *reinterpret_cast<bf4*>(amb + i * 4) = { (__bf16)v.x, (__bf16)v.y, (__bf16)v.z, (__bf16)v.w };
    }
    for (int i = g; i < (MMEM * NH2) / 4; i += T) {
        const float4 v = *reinterpret_cast<const float4*>(nmf + i * 4);
        *reinterpret_cast<bf4*>(nmb + i * 4) = { (__bf16)v.x, (__bf16)v.y, (__bf16)v.z, (__bf16)v.w };
    }
}

// ---------------- GEMM1: h = relu(x @ W1^T + b1) ----------------
// R5 structure, two changes only: B in registers (no B-LDS -> no 64B-row
// conflicts) and A-only tri-buffer 3x16KB = 48KB -> 3 blocks/CU.
// 128x128 tile, BK=32, 4 waves (2x2, wave-tile 64x64), 16 MFMA/wave/step.
// A (x, f32): tri-buffered global_load_lds, 128B rows, chunk^=(row&7) swizzle
//   (verified conflict-free: banks 4*(r&7), 2 lanes/bank). cvt at frag read.
// B (W1, bf16, L2-resident): per-lane direct global 16B fragments,
//   double-buffered in regs, 1-step lookahead.
// Loop: vmcnt(8) [drain A(t); leave A(t+1)+bv] -> barrier -> issue BV(t+1)
//   -> COMPUTE(t) -> STAGE_A(t+2). Never vmcnt(0) in the loop.
__global__ __launch_bounds__(256, 3) void gemm1_kernel(
    const float*  __restrict__ Xf,  // [NROWS][DIM] f32
    const __bf16* __restrict__ W1,  // [NH1][DIM] bf16
    const float*  __restrict__ b1,  // [NH1]
    __bf16* __restrict__ Hout)      // [NROWS][NH1]
{
    __shared__ float As[3][128 * BK];   // 16KB per buffer, 48KB total
    const int tid  = threadIdx.x;
    const int lane = tid & 63;
    const int wave = tid >> 6;
    // XCD swizzle: nwg=512 = 8*64 (bijective).
    const int b = blockIdx.x;
    const int orig = (b & 7) * 64 + (b >> 3);
    const int bn = orig & 3;    // 4 col tiles of 128
    const int bm = orig >> 2;   // 128 row tiles of 128
    const size_t brow = (size_t)bm * 128;
    const int bcol = bn * 128;
    const int wr = wave >> 1, wc = wave & 1;

    f32x4 acc[4][4];
#pragma unroll
    for (int m = 0; m < 4; ++m)
#pragma unroll
        for (int n = 0; n < 4; ++n) acc[m][n] = (f32x4){0.f, 0.f, 0.f, 0.f};

    // ---- A staging: 4 gloads/thread. LDS linear q*4096 + tid*16 ->
    // row = q*32 + (tid>>3), stored slot = tid&7 (128B rows, 8 slots);
    // source chunk = (tid&7) ^ (row&7).
    const int aRowT = tid >> 3;                       // 0..31
    const int cA    = (tid & 7) ^ (aRowT & 7);        // 16B-chunk within 128B row
    const float* aSrcBase = Xf + (brow + aRowT) * (size_t)DIM + cA * 4;

#define STAGE_A(T, BI)                                                        \
    {                                                                         \
        const int k0_ = (T) * BK;                                             \
        _Pragma("unroll")                                                     \
        for (int q = 0; q < 4; ++q)                                           \
            gload_lds16(aSrcBase + (size_t)q * 32 * DIM + k0_,                \
                        (char*)As[BI] + q * 4096 + tid * 16);                 \
    }

    // ---- B direct-from-global fragments (no LDS). One bf16x8 per n-frag.
    const int l15 = lane & 15;
    const int kc  = lane >> 4;
    const int l7  = lane & 7;
    const __bf16* bBase = W1 + (size_t)(bcol + wc * 64 + l15) * DIM + kc * 8;

#define LOAD_BV(T, DST)                                                       \
    {                                                                         \
        _Pragma("unroll")                                                     \
        for (int n = 0; n < 4; ++n)                                           \
            DST[n] = *(const bf16x8*)(bBase + (size_t)(n * 16) * DIM + (T) * BK); \
    }

    // ---- A fragment read (conflict-free): row r = rABase + m*16 (r&7 == l7);
    // logical 16B-chunk c = 2*kc + j  ->  stored slot = c ^ (r&7).
    const int rABase = wr * 64 + l15;
    const int aSlot0 = ((2 * kc)     ^ l7) << 4;
    const int aSlot1 = ((2 * kc + 1) ^ l7) << 4;

#define COMPUTE(BI, BV)                                                       \
    {                                                                         \
        const char* Ac = (const char*)As[BI];                                 \
        bf16x8 av[4];                                                         \
        _Pragma("unroll")                                                     \
        for (int m = 0; m < 4; ++m) {                                         \
            const char* rp = Ac + (rABase + m * 16) * 128;                    \
            f32x4 lo = *(const f32x4*)(rp + aSlot0);                          \
            f32x4 hi = *(const f32x4*)(rp + aSlot1);                          \
            av[m] = cvt8(lo, hi);                                             \
        }                                                                     \
        __builtin_amdgcn_s_setprio(1);                                        \
        _Pragma("unroll")                                                     \
        for (int m = 0; m < 4; ++m)                                           \
            _Pragma("unroll")                                                 \
            for (int n = 0; n < 4; ++n)                                       \
                acc[m][n] = mfma16(av[m], BV[n], acc[m][n]);                  \
        __builtin_amdgcn_s_setprio(0);                                        \
    }

    bf16x8 bva[4], bvb[4];

    // ===== prologue: A(0),A(1) staged; bva = B(0). 12 loads in flight =====
    STAGE_A(0, 0);
    STAGE_A(1, 1);
    LOAD_BV(0, bva);

    // ===== main loop (2x unrolled for static bva/bvb) =====
#pragma unroll 1
    for (int t = 0; t < NT; t += 2) {
        // even half: compute t from buf t%3 with bva
        asm volatile("s_waitcnt vmcnt(8)" ::: "memory");   // A(t) resident
        __builtin_amdgcn_s_barrier();
        __builtin_amdgcn_sched_barrier(0);
        LOAD_BV(t + 1, bvb);
        __builtin_amdgcn_sched_barrier(0);
        COMPUTE(t % 3, bva);
        __builtin_amdgcn_sched_barrier(0);
        {
            const int tA = (t + 2 < NT) ? (t + 2) : (NT - 1);
            STAGE_A(tA, (t + 2) % 3);
        }
        // odd half: compute t+1 from buf (t+1)%3 with bvb
        asm volatile("s_waitcnt vmcnt(8)" ::: "memory");   // A(t+1) resident
        __builtin_amdgcn_s_barrier();
        __builtin_amdgcn_sched_barrier(0);
        if (t + 2 < NT) LOAD_BV(t + 2, bva);
        __builtin_amdgcn_sched_barrier(0);
        COMPUTE((t + 1) % 3, bvb);
        __builtin_amdgcn_sched_barrier(0);
        {
            const int tA = (t + 3 < NT) ? (t + 3) : (NT - 1);
            STAGE_A(tA, (t + 3) % 3);
        }
    }
#undef STAGE_A
#undef LOAD_BV
#undef COMPUTE

    // epilogue: bias + relu + bf16 store. D layout: col=lane&15, row=(lane>>4)*4+reg
#pragma unroll
    for (int n = 0; n < 4; ++n) {
        const int gcol = bcol + wc * 64 + n * 16 + l15;
        const float bias = b1[gcol];
#pragma unroll
        for (int m = 0; m < 4; ++m) {
            const size_t grow0 = brow + wr * 64 + m * 16 + kc * 4;
#pragma unroll
            for (int r = 0; r < 4; ++r) {
                float v = acc[m][n][r] + bias;
                v = v > 0.f ? v : 0.f;
                Hout[(grow0 + r) * NH1 + gcol] = (__bf16)v;
            }
        }
    }
}

// ---------------- Tail: feat = h@W2^T + b2; scores; sigmoid ----------------
__global__ __launch_bounds__(512) void tail_kernel(
    const __bf16* __restrict__ Hin,  // [NROWS][NH1]
    const __bf16* __restrict__ W2b,  // [NH2][NH1]
    const float*  __restrict__ b2,   // [NH2]
    const __bf16* __restrict__ Am,   // [MMEM][NH2]
    const __bf16* __restrict__ Nm,   // [MMEM][NH2]
    float* __restrict__ out)         // [NROWS]
{
    __shared__ __bf16 featLds[64 * 32];
    __shared__ float aMaxLds[2][64];
    __shared__ float nMaxLds[2][64];
    const int tid  = threadIdx.x;
    const int lane = tid & 63;
    const int wave = tid >> 6;          // 0..7
    const int rowBase = blockIdx.x * 64;
    const int l15 = lane & 15;
    const int kc  = lane >> 4;
    const int rgrp  = (wave & 3) * 16;
    const int jHalf = wave >> 2;

    if (wave < 4) {
        f32x4 acc0 = {0.f,0.f,0.f,0.f}, acc1 = {0.f,0.f,0.f,0.f};
        const size_t hrow = (size_t)(rowBase + rgrp + l15) * NH1;
#pragma unroll
        for (int kk = 0; kk < 16; ++kk) {
            bf16x8 a  = *(const bf16x8*)(Hin + hrow + kk * 32 + kc * 8);
            bf16x8 w0 = *(const bf16x8*)(W2b + (size_t)l15 * NH1 + kk * 32 + kc * 8);
            bf16x8 w1 = *(const bf16x8*)(W2b + (size_t)(16 + l15) * NH1 + kk * 32 + kc * 8);
            acc0 = mfma16(a, w0, acc0);
            acc1 = mfma16(a, w1, acc1);
        }
        const float bias0 = b2[l15], bias1 = b2[16 + l15];
#pragma unroll
        for (int r = 0; r < 4; ++r) {
            const int lr = rgrp + kc * 4 + r;
            featLds[lr * 32 + l15]      = (__bf16)(acc0[r] + bias0);
            featLds[lr * 32 + 16 + l15] = (__bf16)(acc1[r] + bias1);
        }
    }
    __syncthreads();

    const bf16x8 af = *(const bf16x8*)&featLds[(rgrp + l15) * 32 + kc * 8];

    float rmaxA[4], rmaxN[4];
#pragma unroll
    for (int r = 0; r < 4; ++r) { rmaxA[r] = -1e30f; rmaxN[r] = -1e30f; }
    const f32x4 zero = {0.f,0.f,0.f,0.f};
    const int jBase = jHalf * (MMEM / 2);
#pragma unroll 2
    for (int jt = 0; jt < (MMEM / 2) / 16; jt += 4) {
        bf16x8 ba[4], bb[4];
#pragma unroll
        for (int u = 0; u < 4; ++u) {
            const size_t off = (size_t)(jBase + (jt + u) * 16 + l15) * NH2 + kc * 8;
            ba[u] = *(const bf16x8*)(Am + off);
            bb[u] = *(const bf16x8*)(Nm + off);
        }
#pragma unroll
        for (int u = 0; u < 4; ++u) {
            f32x4 sa = mfma16(af, ba[u], zero);
            f32x4 sn = mfma16(af, bb[u], zero);
#pragma unroll
            for (int r = 0; r < 4; ++r) {
                rmaxA[r] = fmaxf(rmaxA[r], sa[r]);
                rmaxN[r] = fmaxf(rmaxN[r], sn[r]);
            }
        }
    }
#pragma unroll
    for (int off = 1; off < 16; off <<= 1) {
#pragma unroll
        for (int r = 0; r < 4; ++r) {
            rmaxA[r] = fmaxf(rmaxA[r], __shfl_xor(rmaxA[r], off, 64));
            rmaxN[r] = fmaxf(rmaxN[r], __shfl_xor(rmaxN[r], off, 64));
        }
    }
    if (l15 == 0) {
#pragma unroll
        for (int r = 0; r < 4; ++r) {
            const int row = rgrp + kc * 4 + r;
            aMaxLds[jHalf][row] = rmaxA[r];
            nMaxLds[jHalf][row] = rmaxN[r];
        }
    }
    __syncthreads();
    if (tid < 64) {
        const float ma = fmaxf(aMaxLds[0][tid], aMaxLds[1][tid]);
        const float mn = fmaxf(nMaxLds[0][tid], nMaxLds[1][tid]);
        const float d = (ma - mn) * (1.0f / 32.0f);
        out[rowBase + tid] = 1.0f / (1.0f + __expf(-d));
    }
}

extern "C" void kernel_launch(void* const* d_in, const int* in_sizes, int n_in,
                              void* d_out, int out_size, void* d_ws, size_t ws_size,
                              hipStream_t stream) {
    (void)in_sizes; (void)n_in; (void)out_size; (void)ws_size;
    const float* x  = (const float*)d_in[0];
    const float* W1 = (const float*)d_in[1];
    const float* b1 = (const float*)d_in[2];
    const float* W2 = (const float*)d_in[3];
    const float* b2 = (const float*)d_in[4];
    const float* am = (const float*)d_in[5];
    const float* nm = (const float*)d_in[6];
    float* out = (float*)d_out;
    char* ws = (char*)d_ws;
    __bf16* w1b = (__bf16*)(ws + W1O);
    __bf16* w2b = (__bf16*)(ws + W2O);
    __bf16* amb = (__bf16*)(ws + AMO);
    __bf16* nmb = (__bf16*)(ws + NMO);
    __bf16* hb  = (__bf16*)(ws + HO);

    cvt_all_kernel<<<dim3(512), dim3(256), 0, stream>>>(W1, w1b, W2, w2b, am, amb, nm, nmb);
    gemm1_kernel<<<dim3((NROWS / 128) * (NH1 / 128)), dim3(256), 0, stream>>>(x, w1b, b1, hb);
    tail_kernel<<<dim3(NROWS / 64), dim3(512), 0, stream>>>(hb, w2b, b2, amb, nmb, out);
}

// Round 12
// 81.952 us; speedup vs baseline: 1.3942x; 1.3553x over previous
//
#include <hip/hip_runtime.h>
#include <hip/hip_bf16.h>

typedef __attribute__((ext_vector_type(8))) __bf16 bf16x8;
typedef __attribute__((ext_vector_type(4))) float f32x4;

#define NROWS 16384
#define DIM   2048
#define NH1   512
#define NH2   32
#define MMEM  2048
#define BK    32
#define NT    (DIM / BK)   // 64 K-steps

// workspace byte offsets
#define W1O ((size_t)0)            // W1 bf16:  512*2048*2   = 2097152
#define W2O ((size_t)2097152)      // W2 bf16:  32*512*2     = 32768
#define AMO ((size_t)2129920)      // a_mem:    2048*32*2    = 131072
#define NMO ((size_t)2260992)      // n_mem:    2048*32*2    = 131072
#define HO  ((size_t)2392064)      // h bf16:   16384*512*2  = 16777216

__device__ __forceinline__ f32x4 mfma16(bf16x8 a, bf16x8 b, f32x4 c) {
    return __builtin_amdgcn_mfma_f32_16x16x32_bf16(a, b, c, 0, 0, 0);
}

__device__ __forceinline__ void gload_lds16(const void* g, void* l) {
    __builtin_amdgcn_global_load_lds(
        (const __attribute__((address_space(1))) void*)g,
        (__attribute__((address_space(3))) void*)l, 16, 0, 0);
}

__device__ __forceinline__ bf16x8 cvt8(f32x4 a, f32x4 b) {
    bf16x8 o;
    o[0] = (__bf16)a[0]; o[1] = (__bf16)a[1]; o[2] = (__bf16)a[2]; o[3] = (__bf16)a[3];
    o[4] = (__bf16)b[0]; o[5] = (__bf16)b[1]; o[6] = (__bf16)b[2]; o[7] = (__bf16)b[3];
    return o;
}

// ---------------- merged f32 -> bf16 conversion for W1, W2, am, nm ----------------
struct bf4 { __bf16 a, b, c, d; };

__global__ void cvt_all_kernel(const float* __restrict__ w1f, __bf16* __restrict__ w1b,
                               const float* __restrict__ w2f, __bf16* __restrict__ w2b,
                               const float* __restrict__ amf, __bf16* __restrict__ amb,
                               const float* __restrict__ nmf, __bf16* __restrict__ nmb) {
    const int g = blockIdx.x * blockDim.x + threadIdx.x;
    const int T = gridDim.x * blockDim.x;
    for (int i = g; i < (NH1 * DIM) / 4; i += T) {
        const float4 v = *reinterpret_cast<const float4*>(w1f + i * 4);
        *reinterpret_cast<bf4*>(w1b + i * 4) = { (__bf16)v.x, (__bf16)v.y, (__bf16)v.z, (__bf16)v.w };
    }
    for (int i = g; i < (NH2 * NH1) / 4; i += T) {
        const float4 v = *reinterpret_cast<const float4*>(w2f + i * 4);
        *reinterpret_cast<bf4*>(w2b + i * 4) = { (__bf16)v.x, (__bf16)v.y, (__bf16)v.z, (__bf16)v.w };
    }
    for (int i = g; i < (MMEM * NH2) / 4; i += T) {
        const float4 v = *reinterpret_cast<const float4*>(amf + i * 4);
        *reinterpret_cast<bf4*>(amb + i * 4) = { (__bf16)v.x, (__bf16)v.y, (__bf16)v.z, (__bf16)v.w };
    }
    for (int i = g; i < (MMEM * NH2) / 4; i += T) {
        const float4 v = *reinterpret_cast<const float4*>(nmf + i * 4);
        *reinterpret_cast<bf4*>(nmb + i * 4) = { (__bf16)v.x, (__bf16)v.y, (__bf16)v.z, (__bf16)v.w };
    }
}

// ---------------- GEMM1: h = relu(x @ W1^T + b1) ----------------
// R5 structure verbatim (best measured: 81.7us total), ONE change: B LDS
// layout is row-packed 128B rows (LDS-row R holds W1 tile-rows 2R,2R+1;
// slot ^= (R&7)) -> B ds_read_b128 now 2-way (free) instead of 4-way.
// 128x128 tile, BK=32, 4 waves (2x2, wave-tile 64x64). Tri-buffered LDS,
// BOTH operands staged via global_load_lds (A kept f32, cvt at fragment read).
// One raw s_barrier + counted vmcnt(6) per K-step; stage(t+2) issued after
// compute(t) => ~2 K-steps of latency cover; vmcnt never 0 until last tile.
__global__ __launch_bounds__(256, 2) void gemm1_kernel(
    const float*  __restrict__ Xf,  // [NROWS][DIM] f32
    const __bf16* __restrict__ W1,  // [NH1][DIM] bf16
    const float*  __restrict__ b1,  // [NH1]
    __bf16* __restrict__ Hout)      // [NROWS][NH1]
{
    __shared__ float  As[3][128 * BK];   // 16KB per buffer (f32)
    __shared__ __bf16 Bs[3][128 * BK];   // 8KB per buffer (row-packed 128B rows)
    const int tid  = threadIdx.x;
    const int lane = tid & 63;
    const int wave = tid >> 6;
    // XCD swizzle: nwg=512 = 8*64. XCD c gets orig c*64..c*64+63 (16 row-panels x 4 cols)
    const int b = blockIdx.x;
    const int orig = (b & 7) * 64 + (b >> 3);
    const int bn = orig & 3;    // 4 col tiles of 128
    const int bm = orig >> 2;   // 128 row tiles of 128
    const size_t brow = (size_t)bm * 128;
    const int bcol = bn * 128;
    const int wr = wave >> 1, wc = wave & 1;

    f32x4 acc[4][4];
#pragma unroll
    for (int m = 0; m < 4; ++m)
#pragma unroll
        for (int n = 0; n < 4; ++n) acc[m][n] = (f32x4){0.f, 0.f, 0.f, 0.f};

    // ---- A staging: 4 gloads/thread. s_lin = q*256+tid; row = q*32 + (tid>>3);
    // stored slot = tid&7; source chunk = slot ^ (row&7) = (tid&7)^((tid>>3)&7).
    const int aRowT = tid >> 3;                       // 0..31
    const int cA    = (tid & 7) ^ (aRowT & 7);        // 16B-chunk within 128B row
    const float* aSrcBase = Xf + (brow + aRowT) * (size_t)DIM + cA * 4;
    // ---- B staging: 2 gloads/thread, row-packed layout. Section q in 0..1:
    // LDS byte q*4096 + tid*16 -> LDS-row R = q*32 + (tid>>3), stored slot
    // s = tid&7, logical l = s ^ (R&7) = (tid&7)^((tid>>3)&7); half h = l>>2
    // (which W1 row of the pair), chunk c = l&3 (16B k-chunk).
    // source = W1[(bcol + q*64 + 2*(tid>>3) + h)*DIM + k0 + c*8]
    const int bl  = (tid & 7) ^ ((tid >> 3) & 7);
    const int bh  = bl >> 2;
    const int bc  = bl & 3;
    const __bf16* bSrcBase = W1 + (size_t)(bcol + 2 * (tid >> 3) + bh) * DIM + bc * 8;

#define STAGE(T, BI)                                                          \
    {                                                                         \
        const int k0_ = (T) * BK;                                             \
        _Pragma("unroll")                                                     \
        for (int q = 0; q < 4; ++q)                                           \
            gload_lds16(aSrcBase + (size_t)q * 32 * DIM + k0_,                \
                        (char*)As[BI] + q * 4096 + tid * 16);                 \
        _Pragma("unroll")                                                     \
        for (int q = 0; q < 2; ++q)                                           \
            gload_lds16(bSrcBase + (size_t)q * 64 * DIM + k0_,                \
                        (char*)Bs[BI] + q * 4096 + tid * 16);                 \
    }

    // ---- fragment read geometry (swizzled slots are loop-invariant)
    const int l15 = lane & 15;
    const int kc  = lane >> 4;
    const int l7  = lane & 7;
    const int rABase = wr * 64 + l15;    // (row&7) == l7 for all m-frags
    const int aSlot0 = ((2 * kc)     ^ l7) << 4;
    const int aSlot1 = ((2 * kc + 1) ^ l7) << 4;
    // B read: W1 tile-row rB = wc*64 + n*16 + l15 -> LDS-row R = wc*32 + n*8 +
    // (l15>>1), slot s = ((l15&1)*4 + kc) ^ (l15>>1). Byte = R*128 + s*16.
    const int bByteBase = (wc * 32 + (l15 >> 1)) * 128 +
                          ((((l15 & 1) * 4 + kc) ^ (l15 >> 1)) << 4);

#define COMPUTE(BI)                                                           \
    {                                                                         \
        const char* Ac = (const char*)As[BI];                                 \
        const char* Bc = (const char*)Bs[BI];                                 \
        bf16x8 av[4], bv[4];                                                  \
        _Pragma("unroll")                                                     \
        for (int m = 0; m < 4; ++m) {                                         \
            const int rowB = (rABase + m * 16) * 128;                         \
            f32x4 lo = *(const f32x4*)(Ac + rowB + aSlot0);                   \
            f32x4 hi = *(const f32x4*)(Ac + rowB + aSlot1);                   \
            av[m] = cvt8(lo, hi);                                             \
        }                                                                     \
        _Pragma("unroll")                                                     \
        for (int n = 0; n < 4; ++n)                                           \
            bv[n] = *(const bf16x8*)(Bc + bByteBase + n * 1024);              \
        __builtin_amdgcn_s_setprio(1);                                        \
        _Pragma("unroll")                                                     \
        for (int m = 0; m < 4; ++m)                                           \
            _Pragma("unroll")                                                 \
            for (int n = 0; n < 4; ++n)                                       \
                acc[m][n] = mfma16(av[m], bv[n], acc[m][n]);                  \
        __builtin_amdgcn_s_setprio(0);                                        \
    }

    // ================= prologue: stage tiles 0,1 (12 gloads in flight) ======
    STAGE(0, 0);
    STAGE(1, 1);

    // ================= main loop ===========================================
    // per iter: wait stage(t) [vmcnt(6): leaves stage(t+1)'s 6 in flight],
    // barrier, compute(t), issue stage(t+2). Buffer (t+2)%3 was last read at
    // compute(t-1), protected by this iteration's barrier.
    for (int t = 0; t < NT - 2; ++t) {
        const int bi = t % 3;
        asm volatile("s_waitcnt vmcnt(6)" ::: "memory");
        __builtin_amdgcn_s_barrier();
        __builtin_amdgcn_sched_barrier(0);
        COMPUTE(bi);
        __builtin_amdgcn_sched_barrier(0);
        const int bnx = (t + 2) % 3;
        STAGE(t + 2, bnx);
    }
    // tail: t = NT-2 (outstanding {NT-2, NT-1}), then t = NT-1
    {
        asm volatile("s_waitcnt vmcnt(6)" ::: "memory");
        __builtin_amdgcn_s_barrier();
        __builtin_amdgcn_sched_barrier(0);
        COMPUTE((NT - 2) % 3);
        asm volatile("s_waitcnt vmcnt(0)" ::: "memory");
        __builtin_amdgcn_s_barrier();
        __builtin_amdgcn_sched_barrier(0);
        COMPUTE((NT - 1) % 3);
    }
#undef STAGE
#undef COMPUTE

    // epilogue: bias + relu + bf16 store. D layout: col=lane&15, row=(lane>>4)*4+reg
#pragma unroll
    for (int n = 0; n < 4; ++n) {
        const int gcol = bcol + wc * 64 + n * 16 + l15;
        const float bias = b1[gcol];
#pragma unroll
        for (int m = 0; m < 4; ++m) {
            const size_t grow0 = brow + wr * 64 + m * 16 + kc * 4;
#pragma unroll
            for (int r = 0; r < 4; ++r) {
                float v = acc[m][n][r] + bias;
                v = v > 0.f ? v : 0.f;
                Hout[(grow0 + r) * NH1 + gcol] = (__bf16)v;
            }
        }
    }
}

// ---------------- Tail: feat = h@W2^T + b2; scores; sigmoid ----------------
__global__ __launch_bounds__(512) void tail_kernel(
    const __bf16* __restrict__ Hin,  // [NROWS][NH1]
    const __bf16* __restrict__ W2b,  // [NH2][NH1]
    const float*  __restrict__ b2,   // [NH2]
    const __bf16* __restrict__ Am,   // [MMEM][NH2]
    const __bf16* __restrict__ Nm,   // [MMEM][NH2]
    float* __restrict__ out)         // [NROWS]
{
    __shared__ __bf16 featLds[64 * 32];
    __shared__ float aMaxLds[2][64];
    __shared__ float nMaxLds[2][64];
    const int tid  = threadIdx.x;
    const int lane = tid & 63;
    const int wave = tid >> 6;          // 0..7
    const int rowBase = blockIdx.x * 64;
    const int l15 = lane & 15;
    const int kc  = lane >> 4;
    const int rgrp  = (wave & 3) * 16;
    const int jHalf = wave >> 2;

    if (wave < 4) {
        f32x4 acc0 = {0.f,0.f,0.f,0.f}, acc1 = {0.f,0.f,0.f,0.f};
        const size_t hrow = (size_t)(rowBase + rgrp + l15) * NH1;
#pragma unroll
        for (int kk = 0; kk < 16; ++kk) {
            bf16x8 a  = *(const bf16x8*)(Hin + hrow + kk * 32 + kc * 8);
            bf16x8 w0 = *(const bf16x8*)(W2b + (size_t)l15 * NH1 + kk * 32 + kc * 8);
            bf16x8 w1 = *(const bf16x8*)(W2b + (size_t)(16 + l15) * NH1 + kk * 32 + kc * 8);
            acc0 = mfma16(a, w0, acc0);
            acc1 = mfma16(a, w1, acc1);
        }
        const float bias0 = b2[l15], bias1 = b2[16 + l15];
#pragma unroll
        for (int r = 0; r < 4; ++r) {
            const int lr = rgrp + kc * 4 + r;
            featLds[lr * 32 + l15]      = (__bf16)(acc0[r] + bias0);
            featLds[lr * 32 + 16 + l15] = (__bf16)(acc1[r] + bias1);
        }
    }
    __syncthreads();

    const bf16x8 af = *(const bf16x8*)&featLds[(rgrp + l15) * 32 + kc * 8];

    float rmaxA[4], rmaxN[4];
#pragma unroll
    for (int r = 0; r < 4; ++r) { rmaxA[r] = -1e30f; rmaxN[r] = -1e30f; }
    const f32x4 zero = {0.f,0.f,0.f,0.f};
    const int jBase = jHalf * (MMEM / 2);
#pragma unroll 2
    for (int jt = 0; jt < (MMEM / 2) / 16; jt += 4) {
        bf16x8 ba[4], bb[4];
#pragma unroll
        for (int u = 0; u < 4; ++u) {
            const size_t off = (size_t)(jBase + (jt + u) * 16 + l15) * NH2 + kc * 8;
            ba[u] = *(const bf16x8*)(Am + off);
            bb[u] = *(const bf16x8*)(Nm + off);
        }
#pragma unroll
        for (int u = 0; u < 4; ++u) {
            f32x4 sa = mfma16(af, ba[u], zero);
            f32x4 sn = mfma16(af, bb[u], zero);
#pragma unroll
            for (int r = 0; r < 4; ++r) {
                rmaxA[r] = fmaxf(rmaxA[r], sa[r]);
                rmaxN[r] = fmaxf(rmaxN[r], sn[r]);
            }
        }
    }
#pragma unroll
    for (int off = 1; off < 16; off <<= 1) {
#pragma unroll
        for (int r = 0; r < 4; ++r) {
            rmaxA[r] = fmaxf(rmaxA[r], __shfl_xor(rmaxA[r], off, 64));
            rmaxN[r] = fmaxf(rmaxN[r], __shfl_xor(rmaxN[r], off, 64));
        }
    }
    if (l15 == 0) {
#pragma unroll
        for (int r = 0; r < 4; ++r) {
            const int row = rgrp + kc * 4 + r;
            aMaxLds[jHalf][row] = rmaxA[r];
            nMaxLds[jHalf][row] = rmaxN[r];
        }
    }
    __syncthreads();
    if (tid < 64) {
        const float ma = fmaxf(aMaxLds[0][tid], aMaxLds[1][tid]);
        const float mn = fmaxf(nMaxLds[0][tid], nMaxLds[1][tid]);
        const float d = (ma - mn) * (1.0f / 32.0f);
        out[rowBase + tid] = 1.0f / (1.0f + __expf(-d));
    }
}

extern "C" void kernel_launch(void* const* d_in, const int* in_sizes, int n_in,
                              void* d_out, int out_size, void* d_ws, size_t ws_size,
                              hipStream_t stream) {
    (void)in_sizes; (void)n_in; (void)out_size; (void)ws_size;
    const float* x  = (const float*)d_in[0];
    const float* W1 = (const float*)d_in[1];
    const float* b1 = (const float*)d_in[2];
    const float* W2 = (const float*)d_in[3];
    const float* b2 = (const float*)d_in[4];
    const float* am = (const float*)d_in[5];
    const float* nm = (const float*)d_in[6];
    float* out = (float*)d_out;
    char* ws = (char*)d_ws;
    __bf16* w1b = (__bf16*)(ws + W1O);
    __bf16* w2b = (__bf16*)(ws + W2O);
    __bf16* amb = (__bf16*)(ws + AMO);
    __bf16* nmb = (__bf16*)(ws + NMO);
    __bf16* hb  = (__bf16*)(ws + HO);

    cvt_all_kernel<<<dim3(512), dim3(256), 0, stream>>>(W1, w1b, W2, w2b, am, amb, nm, nmb);
    gemm1_kernel<<<dim3((NROWS / 128) * (NH1 / 128)), dim3(256), 0, stream>>>(x, w1b, b1, hb);
    tail_kernel<<<dim3(NROWS / 64), dim3(512), 0, stream>>>(hb, w2b, b2, amb, nmb, out);
}